// Round 2
// baseline (171.883 us; speedup 1.0000x reference)
//
#include <hip/hip_runtime.h>

constexpr int kNodes = 50000;
constexpr int kEdges = 500000;
constexpr int kInF   = 128;
constexpr int kOutF  = 16;

typedef float f32x4 __attribute__((ext_vector_type(4)));

// ---------------------------------------------------------------------------
// Kernel 1 (fused): support[n][f] = sum_k x[n][k]*W[k][f]  AND  out[n][f]=bias[f]
// 4 threads per node; thread owns one float4 (f4) of the 16 outputs.
// 200k threads -> ~12 waves/CU so the 26 MB x stream is latency-hidden.
// Sibling threads (same node, f4=0..3) read the same x row -> L1 broadcast.
// ---------------------------------------------------------------------------
__global__ __launch_bounds__(256) void support_init_kernel(
    const float* __restrict__ x, const float* __restrict__ weight,
    const float* __restrict__ bias, float* __restrict__ support,
    float* __restrict__ out) {
  __shared__ f32x4 w4[kInF][kOutF / 4];  // w4[k][f4]
  for (int i = threadIdx.x; i < kInF * (kOutF / 4); i += 256) {
    w4[i / (kOutF / 4)][i % (kOutF / 4)] =
        reinterpret_cast<const f32x4*>(weight)[i];
  }
  __shared__ f32x4 b4[kOutF / 4];
  if (threadIdx.x < kOutF / 4)
    b4[threadIdx.x] = reinterpret_cast<const f32x4*>(bias)[threadIdx.x];
  __syncthreads();

  const int gid  = blockIdx.x * 256 + threadIdx.x;
  const int node = gid >> 2;
  const int f4   = gid & 3;
  if (node >= kNodes) return;

  f32x4 acc = {0.f, 0.f, 0.f, 0.f};
  const f32x4* xr = reinterpret_cast<const f32x4*>(x + (size_t)node * kInF);
#pragma unroll
  for (int k4 = 0; k4 < kInF / 4; ++k4) {
    const f32x4 v = xr[k4];
#pragma unroll
    for (int kk = 0; kk < 4; ++kk) {
      acc += v[kk] * w4[k4 * 4 + kk][f4];
    }
  }

  reinterpret_cast<f32x4*>(support + (size_t)node * kOutF)[f4] = acc;
  reinterpret_cast<f32x4*>(out + (size_t)node * kOutF)[f4] = b4[f4];
}

// ---------------------------------------------------------------------------
// Kernel 2: per-edge 16x16 matvec + atomic scatter onto target nodes.
// 16 lanes per edge; lane i owns output row i (64 B contiguous per lane,
// 4 KB contiguous per wave). edge_data (512 MB) is streamed nontemporally
// so support/out stay L2-resident for the gather + atomics.
// ---------------------------------------------------------------------------
__global__ __launch_bounds__(256) void edge_kernel(
    const float* __restrict__ edge_data, const float* __restrict__ support,
    const int* __restrict__ esrc, const int* __restrict__ etgt,
    float* __restrict__ out) {
  const int gid = blockIdx.x * 256 + threadIdx.x;
  const int e = gid >> 4;
  const int i = gid & 15;
  if (e >= kEdges) return;

  const int src = esrc[e];
  const int tgt = etgt[e];

  const f32x4* s4 =
      reinterpret_cast<const f32x4*>(support + (size_t)src * kOutF);
  const f32x4 s0 = s4[0], s1 = s4[1], s2 = s4[2], s3 = s4[3];

  const f32x4* ed = reinterpret_cast<const f32x4*>(
      edge_data + (size_t)e * (kOutF * kOutF) + (size_t)i * kOutF);
  const f32x4 r0 = __builtin_nontemporal_load(ed + 0);
  const f32x4 r1 = __builtin_nontemporal_load(ed + 1);
  const f32x4 r2 = __builtin_nontemporal_load(ed + 2);
  const f32x4 r3 = __builtin_nontemporal_load(ed + 3);

  float acc = r0.x * s0.x + r0.y * s0.y + r0.z * s0.z + r0.w * s0.w;
  acc      += r1.x * s1.x + r1.y * s1.y + r1.z * s1.z + r1.w * s1.w;
  acc      += r2.x * s2.x + r2.y * s2.y + r2.z * s2.z + r2.w * s2.w;
  acc      += r3.x * s3.x + r3.y * s3.y + r3.z * s3.z + r3.w * s3.w;

  atomicAdd(&out[(size_t)tgt * kOutF + i], acc);
}

// ---------------------------------------------------------------------------
extern "C" void kernel_launch(void* const* d_in, const int* in_sizes, int n_in,
                              void* d_out, int out_size, void* d_ws,
                              size_t ws_size, hipStream_t stream) {
  const float* x         = (const float*)d_in[0];
  const float* weight    = (const float*)d_in[1];
  const float* bias      = (const float*)d_in[2];
  const float* edge_data = (const float*)d_in[3];
  const int*   esrc      = (const int*)d_in[4];
  const int*   etgt      = (const int*)d_in[5];
  float* out = (float*)d_out;

  float* support = (float*)d_ws;  // kNodes * kOutF * 4 B = 3.2 MB

  support_init_kernel<<<(kNodes * 4 + 255) / 256, 256, 0, stream>>>(
      x, weight, bias, support, out);
  edge_kernel<<<(kEdges * 16 + 255) / 256, 256, 0, stream>>>(
      edge_data, support, esrc, etgt, out);
}

// Round 3
// 112.159 us; speedup vs baseline: 1.5325x; 1.5325x over previous
//
#include <hip/hip_runtime.h>

constexpr int kNodes = 50000;
constexpr int kEdges = 500000;
constexpr int kInF   = 128;
constexpr int kOutF  = 16;

typedef float f32x4 __attribute__((ext_vector_type(4)));

// ---------------------------------------------------------------------------
// Kernel 1 (fused): support[n][f] = sum_k x[n][k]*W[k][f]  AND  out[n][f]=bias[f]
// 4 threads per node; thread owns one float4 (f4) of the 16 outputs.
// 200k threads -> ~12 waves/CU; x row reads are L1-broadcast across the 4
// sibling threads.
// ---------------------------------------------------------------------------
__global__ __launch_bounds__(256) void support_init_kernel(
    const float* __restrict__ x, const float* __restrict__ weight,
    const float* __restrict__ bias, float* __restrict__ support,
    float* __restrict__ out) {
  __shared__ f32x4 w4[kInF][kOutF / 4];  // w4[k][f4]
  for (int i = threadIdx.x; i < kInF * (kOutF / 4); i += 256) {
    w4[i / (kOutF / 4)][i % (kOutF / 4)] =
        reinterpret_cast<const f32x4*>(weight)[i];
  }
  __shared__ f32x4 b4[kOutF / 4];
  if (threadIdx.x < kOutF / 4)
    b4[threadIdx.x] = reinterpret_cast<const f32x4*>(bias)[threadIdx.x];
  __syncthreads();

  const int gid  = blockIdx.x * 256 + threadIdx.x;
  const int node = gid >> 2;
  const int f4   = gid & 3;
  if (node >= kNodes) return;

  f32x4 acc = {0.f, 0.f, 0.f, 0.f};
  const f32x4* xr = reinterpret_cast<const f32x4*>(x + (size_t)node * kInF);
#pragma unroll
  for (int k4 = 0; k4 < kInF / 4; ++k4) {
    const f32x4 v = xr[k4];
#pragma unroll
    for (int kk = 0; kk < 4; ++kk) {
      acc += v[kk] * w4[k4 * 4 + kk][f4];
    }
  }

  reinterpret_cast<f32x4*>(support + (size_t)node * kOutF)[f4] = acc;
  reinterpret_cast<f32x4*>(out + (size_t)node * kOutF)[f4] = b4[f4];
}

// ---------------------------------------------------------------------------
// Kernel 2: per-edge 16x16 matvec + atomic scatter onto target nodes.
// 16 lanes per edge; lane i owns output row i (64 B contiguous per lane,
// 4 KB contiguous per wave). Plain cached loads: edge_data partially
// L3-resident across replays; support/out stay L2-hot via normal LRU.
// ---------------------------------------------------------------------------
__global__ __launch_bounds__(256) void edge_kernel(
    const float* __restrict__ edge_data, const float* __restrict__ support,
    const int* __restrict__ esrc, const int* __restrict__ etgt,
    float* __restrict__ out) {
  const int gid = blockIdx.x * 256 + threadIdx.x;
  const int e = gid >> 4;
  const int i = gid & 15;
  if (e >= kEdges) return;

  const int src = esrc[e];
  const int tgt = etgt[e];

  const f32x4* s4 =
      reinterpret_cast<const f32x4*>(support + (size_t)src * kOutF);
  const f32x4 s0 = s4[0], s1 = s4[1], s2 = s4[2], s3 = s4[3];

  const f32x4* ed = reinterpret_cast<const f32x4*>(
      edge_data + (size_t)e * (kOutF * kOutF) + (size_t)i * kOutF);
  const f32x4 r0 = ed[0], r1 = ed[1], r2 = ed[2], r3 = ed[3];

  float acc = r0.x * s0.x + r0.y * s0.y + r0.z * s0.z + r0.w * s0.w;
  acc      += r1.x * s1.x + r1.y * s1.y + r1.z * s1.z + r1.w * s1.w;
  acc      += r2.x * s2.x + r2.y * s2.y + r2.z * s2.z + r2.w * s2.w;
  acc      += r3.x * s3.x + r3.y * s3.y + r3.z * s3.z + r3.w * s3.w;

  atomicAdd(&out[(size_t)tgt * kOutF + i], acc);
}

// ---------------------------------------------------------------------------
extern "C" void kernel_launch(void* const* d_in, const int* in_sizes, int n_in,
                              void* d_out, int out_size, void* d_ws,
                              size_t ws_size, hipStream_t stream) {
  const float* x         = (const float*)d_in[0];
  const float* weight    = (const float*)d_in[1];
  const float* bias      = (const float*)d_in[2];
  const float* edge_data = (const float*)d_in[3];
  const int*   esrc      = (const int*)d_in[4];
  const int*   etgt      = (const int*)d_in[5];
  float* out = (float*)d_out;

  float* support = (float*)d_ws;  // kNodes * kOutF * 4 B = 3.2 MB

  support_init_kernel<<<(kNodes * 4 + 255) / 256, 256, 0, stream>>>(
      x, weight, bias, support, out);
  edge_kernel<<<(kEdges * 16 + 255) / 256, 256, 0, stream>>>(
      edge_data, support, esrc, etgt, out);
}